// Round 2
// 203.919 us; speedup vs baseline: 1.2469x; 1.2469x over previous
//
#include <hip/hip_runtime.h>
#include <math.h>

// Round 8 (= round 7 with compile fix): binary-spike LUT conv.
// The conv input z is {0,1}, so the dense 64-pk_fma 4x4x2ch conv is replaced
// by a 5-bit-row table lookup:
//   - encoder lanes remapped so __ballot() produces row-aligned bitplanes:
//     lane w owns pixel (row=4k+(w>>4), col=w&15) for k=0..3; ballot k packs
//     rows 4k..4k+3 as 16-bit fields (col15/row15 lanes forced inactive).
//     s_bits word m = row 2m (lo16) | row 2m+1 (hi16).
//   - __ballot returns the full 64-bit mask to ALL lanes, so lanes 0..7 just
//     select their half via a branchless cndmask tree (no writelane builtin
//     on this toolchain, and no runtime-indexed array -> no scratch).
//   - s_lut[ky][n] (n = 5 row bits at cols 2px..2px+4) = float4
//     {ch0@dx0, ch1@dx0, ch0@dx1, ch1@dx1} row-weight sums, built once.
//   - per pooled output: 3 broadcast word reads + 5 bit extracts +
//     8 ds_read_b128 gathers + 16 pk_add replace 25 strided ds_read +
//     64 pk_fma (the old s_z swizzle + its 2e7 bank conflicts are gone).
// Wave1 (linear+decoder), the 4-step/1-barrier pipeline, s_p 8-deep handoff
// and deferred global stores are byte-identical to round 6. Requires T%4==0.

typedef float v2f __attribute__((ext_vector_type(2)));

__global__ __launch_bounds__(128, 4) void snn_step_kernel(
    const float* __restrict__ x,       // [B,1,15,15]
    const float* __restrict__ conv_w,  // [2,1,4,4]
    const float* __restrict__ conv_b,  // [2]
    const float* __restrict__ lin_w,   // [10,72]
    const float* __restrict__ lin_b,   // [10]
    float* __restrict__ out,           // spk_out[B,10] ++ mem_rec[T,B,10] ++ spk_rec[T,B,10]
    int T, int B)
{
    const int b   = blockIdx.x;
    const int tid = threadIdx.x;
    const int w   = tid & 63;   // lane within wave
    const int wv  = tid >> 6;   // 0 = enc+conv wave, 1 = lin+dec wave

    __shared__ float  s_linw[720];
    __shared__ float  s_linb[10];
    __shared__ float4 s_lut[4][32];        // [ky][5-bit row bits] -> 4 partial sums
    __shared__ unsigned int s_bits[2][16]; // double-buffered packed spike rows
    __shared__ float  s_p[8][72];          // wave0 -> wave1 handoff, 8-deep
    __shared__ float  s_part[64];          // wave1-private

    // ---- cooperative staging: lin weights + conv LUT (128 threads) ----
    for (int j = tid; j < 720; j += 128) s_linw[j] = lin_w[j];
    if (tid < 10) s_linb[tid] = lin_b[tid];
    {
        const int ky = tid >> 5, n = tid & 31;   // 128 threads = 4 ky x 32 patterns
        float s00 = 0.f, s01 = 0.f, s10 = 0.f, s11 = 0.f;
#pragma unroll
        for (int kx = 0; kx < 4; ++kx) {
            const float w0 = conv_w[ky * 4 + kx];        // ch0
            const float w1 = conv_w[16 + ky * 4 + kx];   // ch1
            if ((n >> kx) & 1)       { s00 += w0; s01 += w1; }  // dx = 0
            if ((n >> (kx + 1)) & 1) { s10 += w0; s11 += w1; }  // dx = 1
        }
        s_lut[ky][n] = make_float4(s00, s01, s10, s11);
    }
    __syncthreads();

    // ===== wave0 state =====
    float ve[4], cur[4];
    v2f  cb2 = (v2f){0.f, 0.f};
    bool convlane = false;
    int  wordsel = 0, shx = 0, shx16 = 16;

    // ===== wave1 state =====
    float lwreg[18];
    float lbias = 0.f;
    float v = 0.f, i_syn = 0.f, sc = 0.f;
    float svv[4], svs[4];           // deferred store values (v_new, spk) per k
    const int lo = w >> 2, lq = w & 3;
    const size_t BO = (size_t)B * 10;
    float* mp  = out + BO + (size_t)b * 10 + w;
    float* spp = out + BO + (size_t)T * BO + (size_t)b * 10 + w;

    // encoder step for all 64 lanes + ballot bit-pack -> s_bits[bufsel]
    auto enc_pack = [&](int bufsel) {
        unsigned long long bal0, bal1, bal2, bal3;
        {
            float vn = __fadd_rn(ve[0], __fmul_rn(0.1f, __fsub_rn(cur[0], ve[0])));
            bool  sp = (vn > 1.0f);
            ve[0] = sp ? 0.f : vn;
            bal0  = __ballot(sp);
        }
        {
            float vn = __fadd_rn(ve[1], __fmul_rn(0.1f, __fsub_rn(cur[1], ve[1])));
            bool  sp = (vn > 1.0f);
            ve[1] = sp ? 0.f : vn;
            bal1  = __ballot(sp);
        }
        {
            float vn = __fadd_rn(ve[2], __fmul_rn(0.1f, __fsub_rn(cur[2], ve[2])));
            bool  sp = (vn > 1.0f);
            ve[2] = sp ? 0.f : vn;
            bal2  = __ballot(sp);
        }
        {
            float vn = __fadd_rn(ve[3], __fmul_rn(0.1f, __fsub_rn(cur[3], ve[3])));
            bool  sp = (vn > 1.0f);
            ve[3] = sp ? 0.f : vn;
            bal3  = __ballot(sp);
        }
        // every lane holds all 4 masks (wave-uniform); lanes 0..7 pick theirs
        unsigned long long m01 = (w & 2) ? bal1 : bal0;
        unsigned long long m23 = (w & 2) ? bal3 : bal2;
        unsigned long long m   = (w & 4) ? m23 : m01;
        unsigned word = (unsigned)((w & 1) ? (m >> 32) : m);
        if (w < 8) s_bits[bufsel][w] = word;
    };

    if (wv == 0) {
        // encoder lane mapping: pixel (row = 4k + (w>>4), col = w&15)
        const int j   = w >> 4;
        const int col = w & 15;
#pragma unroll
        for (int k = 0; k < 4; ++k) {
            const int  row = 4 * k + j;
            const bool act = (col < 15) && (row < 15);
            ve[k]  = 0.f;
            cur[k] = act ? __fmul_rn(x[(size_t)b * 225 + row * 15 + col], 10.0f) : 0.f;
        }
        convlane = (w < 36);
        const int py = w / 6, px = w - 6 * py;   // pooled output coords
        wordsel = py;          // words py..py+2 hold rows 2py..2py+5
        shx     = 2 * px;      // 5-bit window starts at col 2px
        shx16   = shx + 16;
        cb2 = (v2f){conv_b[0], conv_b[1]};

        enc_pack(0);   // prologue: step-0 spikes -> s_bits[0]
    } else {
#pragma unroll
        for (int jj = 0; jj < 18; ++jj) {
            int idx = lo * 72 + lq * 18 + jj;
            lwreg[jj] = s_linw[idx < 720 ? idx : 719];   // clamp for lanes >= 40
        }
        lbias = (w < 10) ? s_linb[w] : 0.f;
    }

    // wave1: linear+decoder compute for one step; stores deferred into svv/svs[k]
    auto lin_comp = [&](const float* pbuf, int k) {
        const float* pp = &pbuf[lq * 18];
        float pv[18];
#pragma unroll
        for (int jj = 0; jj < 18; ++jj) pv[jj] = pp[jj];
        float partial = 0.0f;
#pragma unroll
        for (int jj = 0; jj < 18; ++jj)
            partial = fmaf(lwreg[jj], pv[jj], partial);
        s_part[w] = partial;

        float vd  = __fadd_rn(v, __fmul_rn(0.1f, __fsub_rn(i_syn, v)));
        float id  = __fsub_rn(i_syn, __fmul_rn(0.2f, i_syn));
        float spk = (vd > 1.0f) ? 1.0f : 0.0f;
        v = (vd > 1.0f) ? 0.0f : vd;
        sc += spk;
        svv[k] = v;
        svs[k] = spk;

        float4 pr = *(const float4*)&s_part[4 * (w < 10 ? w : 0)];
        float lin = __fadd_rn(__fadd_rn(__fadd_rn(__fadd_rn(pr.x, pr.y), pr.z), pr.w), lbias);
        i_syn = __fadd_rn(id, lin);
    };

    auto issue_stores = [&]() {
        if (w < 10) {
#pragma unroll
            for (int k = 0; k < 4; ++k) {
                mp[(size_t)k * BO]  = svv[k];
                spp[(size_t)k * BO] = svs[k];
            }
        }
        mp  += 4 * BO;
        spp += 4 * BO;
    };

    const int TI = T >> 2;   // T % 4 == 0

    for (int i = 0; i < TI; ++i) {
        if (wv == 0) {
#pragma unroll
            for (int k = 0; k < 4; ++k) {
                // packed rows for step s=4i+k (broadcast across px groups)
                unsigned wb0 = 0, wb1 = 0, wb2 = 0;
                if (convlane) {
                    const unsigned* bb = &s_bits[k & 1][wordsel];
                    wb0 = bb[0]; wb1 = bb[1]; wb2 = bb[2];
                }

                // encoder for step s+1 -> s_bits[(k+1)&1] (hides read latency)
                enc_pack((k + 1) & 1);

                if (convlane) {
                    // 5-bit window-row patterns for rows 2py .. 2py+4
                    const int i0 = (wb0 >> shx)   & 31;
                    const int i1 = (wb0 >> shx16) & 31;
                    const int i2 = (wb1 >> shx)   & 31;
                    const int i3 = (wb1 >> shx16) & 31;
                    const int i4 = (wb2 >> shx)   & 31;

                    // dy=0 windows use rows ky, dy=1 windows rows ky+1
                    const float4 f0 = s_lut[0][i0];
                    const float4 f1 = s_lut[1][i1];
                    const float4 f2 = s_lut[2][i2];
                    const float4 f3 = s_lut[3][i3];
                    const float4 g0 = s_lut[0][i1];
                    const float4 g1 = s_lut[1][i2];
                    const float4 g2 = s_lut[2][i3];
                    const float4 g3 = s_lut[3][i4];

                    v2f a00 = (v2f){f0.x, f0.y};  a00 += (v2f){f1.x, f1.y};
                    a00 += (v2f){f2.x, f2.y};     a00 += (v2f){f3.x, f3.y};
                    v2f a01 = (v2f){f0.z, f0.w};  a01 += (v2f){f1.z, f1.w};
                    a01 += (v2f){f2.z, f2.w};     a01 += (v2f){f3.z, f3.w};
                    v2f a10 = (v2f){g0.x, g0.y};  a10 += (v2f){g1.x, g1.y};
                    a10 += (v2f){g2.x, g2.y};     a10 += (v2f){g3.x, g3.y};
                    v2f a11 = (v2f){g0.z, g0.w};  a11 += (v2f){g1.z, g1.w};
                    a11 += (v2f){g2.z, g2.w};     a11 += (v2f){g3.z, g3.w};

                    v2f v00 = a00 + cb2, v01 = a01 + cb2;
                    v2f v10 = a10 + cb2, v11 = a11 + cb2;
                    v2f m2 = __builtin_elementwise_max(
                                 __builtin_elementwise_max(v00, v01),
                                 __builtin_elementwise_max(v10, v11));

                    float* pbuf = s_p[((i & 1) << 2) | k];
                    pbuf[w]      = m2.x;
                    pbuf[36 + w] = m2.y;
                }
            }
        } else {
            if (i >= 2) issue_stores();        // steps 4(i-2)..4(i-2)+3
            if (i >= 1) {
#pragma unroll
                for (int k = 0; k < 4; ++k)    // steps 4(i-1)..4(i-1)+3
                    lin_comp(s_p[(((i - 1) & 1) << 2) | k], k);
            }
        }
        __syncthreads();
    }

    // ---- epilogue (wave1): pending stores T-8..T-5, compute+store T-4..T-1 ----
    if (wv == 1) {
        issue_stores();                         // steps T-8..T-5
#pragma unroll
        for (int k = 0; k < 4; ++k)             // steps T-4..T-1
            lin_comp(s_p[(((TI - 1) & 1) << 2) | k], k);
        issue_stores();
        if (w < 10) out[(size_t)b * 10 + w] = sc;
    }
}

extern "C" void kernel_launch(void* const* d_in, const int* in_sizes, int n_in,
                              void* d_out, int out_size, void* d_ws, size_t ws_size,
                              hipStream_t stream) {
    const float* x      = (const float*)d_in[0];
    const float* conv_w = (const float*)d_in[1];
    const float* conv_b = (const float*)d_in[2];
    const float* lin_w  = (const float*)d_in[3];
    const float* lin_b  = (const float*)d_in[4];
    float* out = (float*)d_out;

    const int B = in_sizes[0] / 225;             // x is [B,1,15,15]
    const int T = (out_size / (B * 10) - 1) / 2; // out = B*10 * (1 + 2T); T=300 (div by 4)

    snn_step_kernel<<<B, 128, 0, stream>>>(x, conv_w, conv_b, lin_w, lin_b, out, T, B);
}